// Round 1
// baseline (89.200 us; speedup 1.0000x reference)
//
#include <hip/hip_runtime.h>
#include <math.h>

struct c2 { float re, im; };
__device__ inline c2 cmul(c2 a, c2 b){ return {a.re*b.re - a.im*b.im, a.re*b.im + a.im*b.re}; }
__device__ inline c2 cadd(c2 a, c2 b){ return {a.re+b.re, a.im+b.im}; }

// Block: 256 threads = 4 waves. Each wave handles 4 samples -> 16 samples/block.
// LDS table: 832 pixels (784 + pad) x 12 floats: [alpha, beta, w[0..9] permuted].
__global__ __launch_bounds__(256) void quanv_kernel(
    const float* __restrict__ x, const float* __restrict__ params,
    const float* __restrict__ w, const float* __restrict__ bias,
    float* __restrict__ out, int Bn)
{
    __shared__ __align__(16) float tab[832 * 12];
    __shared__ float wls[4][40];

    const int tid  = threadIdx.x;
    const int lane = tid & 63;
    const int wid  = tid >> 6;

    // ---- per-block (uniform) SU(2) composition: alpha_q, beta_q ----
    float Aq[4], Bq[4];
    #pragma unroll
    for (int q = 0; q < 4; ++q) {
        c2 m00 = {1.f, 0.f}, m01 = {0.f, 0.f}, m10 = {0.f, 0.f}, m11 = {1.f, 0.f};
        #pragma unroll
        for (int d = 0; d < 4; ++d) {
            float rz1 = params[(d * 4 + q) * 3 + 0];
            float ry  = params[(d * 4 + q) * 3 + 1];
            float rz2 = params[(d * 4 + q) * 3 + 2];
            float c  = __cosf(0.5f * ry),  s  = __sinf(0.5f * ry);
            c2 ph1  = { __cosf(0.5f * rz1), -__sinf(0.5f * rz1) };  // e^{-i rz1/2}
            c2 ph1c = { ph1.re, -ph1.im };
            c2 ph2  = { __cosf(0.5f * rz2), -__sinf(0.5f * rz2) };
            c2 ph2c = { ph2.re, -ph2.im };
            c2 d00 = cmul(ph2,  { c * ph1.re,  c * ph1.im });
            c2 d01 = cmul(ph2,  {-s * ph1c.re, -s * ph1c.im});
            c2 d10 = cmul(ph2c, { s * ph1.re,  s * ph1.im });
            c2 d11 = cmul(ph2c, { c * ph1c.re, c * ph1c.im});
            c2 n00 = cadd(cmul(d00, m00), cmul(d01, m10));
            c2 n01 = cadd(cmul(d00, m01), cmul(d01, m11));
            c2 n10 = cadd(cmul(d10, m00), cmul(d11, m10));
            c2 n11 = cadd(cmul(d10, m01), cmul(d11, m11));
            m00 = n00; m01 = n01; m10 = n10; m11 = n11;
        }
        float n00 = m00.re*m00.re + m00.im*m00.im;
        float n10 = m10.re*m10.re + m10.im*m10.im;
        float n01 = m01.re*m01.re + m01.im*m01.im;
        float n11 = m11.re*m11.re + m11.im*m11.im;
        Aq[q] = 0.5f * (n00 - n10 - n01 + n11);
        Bq[q] = (m00.re*m01.re + m00.im*m01.im) - (m10.re*m11.re + m10.im*m11.im);
    }

    // ---- build LDS table ----
    for (int m = tid; m < 832; m += 256) {
        if (m < 784) {
            int r = m / 28, col = m - 28 * r;
            int q = ((r & 1) << 1) | (col & 1);
            tab[m * 12 + 0] = Aq[q];
            tab[m * 12 + 1] = Bq[q];
        } else {
            #pragma unroll
            for (int k = 0; k < 12; ++k) tab[m * 12 + k] = 0.f;
        }
    }
    // weights, coalesced read; scatter through inverse patch permutation
    for (int idx = tid; idx < 7840; idx += 256) {
        int c = idx / 784, f = idx - 784 * c;
        int p = f >> 2, q = f & 3;
        int pi = p / 14, pj = p - 14 * pi;
        int r = 2 * pi + (q >> 1), col = 2 * pj + (q & 1);
        int m = r * 28 + col;
        tab[m * 12 + 2 + c] = w[idx];
    }
    __syncthreads();

    const float4* tab4 = (const float4*)tab;

    // ---- main accumulation: 4 samples per wave ----
    int b0 = blockIdx.x * 16 + wid * 4;
    const float* xr[4];
    #pragma unroll
    for (int s = 0; s < 4; ++s) {
        int bs = b0 + s; if (bs > Bn - 1) bs = Bn - 1;
        xr[s] = x + (size_t)bs * 784;
    }

    float acc[4][10];
    #pragma unroll
    for (int s = 0; s < 4; ++s)
        #pragma unroll
        for (int c = 0; c < 10; ++c) acc[s][c] = 0.f;

    for (int it = 0; it < 13; ++it) {
        int m = it * 64 + lane;
        int mm = m < 784 ? m : 783;          // padded table rows are zero -> no contribution
        float4 t0 = tab4[m * 3 + 0];
        float4 t1 = tab4[m * 3 + 1];
        float4 t2 = tab4[m * 3 + 2];
        float al = t0.x, be = t0.y;
        float wg[10] = {t0.z, t0.w, t1.x, t1.y, t1.z, t1.w, t2.x, t2.y, t2.z, t2.w};
        float xv[4];
        #pragma unroll
        for (int s = 0; s < 4; ++s) xv[s] = xr[s][mm];
        #pragma unroll
        for (int s = 0; s < 4; ++s) {
            float cs = __cosf(xv[s]);
            float sn = __sinf(xv[s]);
            float z  = al * cs + be * sn;
            #pragma unroll
            for (int c = 0; c < 10; ++c) acc[s][c] = fmaf(z, wg[c], acc[s][c]);
        }
    }

    // ---- wave butterfly reduction ----
    #pragma unroll
    for (int s = 0; s < 4; ++s) {
        #pragma unroll
        for (int c = 0; c < 10; ++c) {
            float v = acc[s][c];
            v += __shfl_xor(v, 32, 64);
            v += __shfl_xor(v, 16, 64);
            v += __shfl_xor(v,  8, 64);
            v += __shfl_xor(v,  4, 64);
            v += __shfl_xor(v,  2, 64);
            v += __shfl_xor(v,  1, 64);
            if (lane == 0) wls[wid][s * 10 + c] = v;
        }
    }
    __syncthreads();

    // ---- log_softmax epilogue: lanes 0..39, one (sample, class) each ----
    if (lane < 40) {
        int s = lane / 10, c = lane - 10 * s;
        const float* L = &wls[wid][s * 10];
        float mx = -1e30f;
        #pragma unroll
        for (int k = 0; k < 10; ++k) { float v = L[k] + bias[k]; mx = fmaxf(mx, v); }
        float sum = 0.f;
        #pragma unroll
        for (int k = 0; k < 10; ++k) sum += __expf(L[k] + bias[k] - mx);
        float lse = mx + __logf(sum);
        int b = b0 + s;
        if (b < Bn) out[b * 10 + c] = (L[c] + bias[c]) - lse;
    }
}

extern "C" void kernel_launch(void* const* d_in, const int* in_sizes, int n_in,
                              void* d_out, int out_size, void* d_ws, size_t ws_size,
                              hipStream_t stream) {
    const float* x      = (const float*)d_in[0];
    const float* params = (const float*)d_in[1];
    const float* w      = (const float*)d_in[2];
    const float* bias   = (const float*)d_in[3];
    float* out = (float*)d_out;
    int Bn = in_sizes[0] / 784;
    int grid = (Bn + 15) / 16;
    quanv_kernel<<<grid, 256, 0, stream>>>(x, params, w, bias, out, Bn);
}